// Round 10
// baseline (56.546 us; speedup 1.0000x reference)
//
#include <hip/hip_runtime.h>
#include <hip/hip_bf16.h>

// Chamfer loss via 32x32x16 MFMA — TWO dispatches total.
// predict_pc [B=4,3,N=8192] f32, gt_pc [B,3,N] f32.
// loss = sum_gt min_pred d / B + sum_pred min_gt d / B
//
// m := d^2/2 = on + qn - o.q via bf16 MFMA 32x32x16, split-bf16 (hi+lo ~fp32).
// Records (16 shorts, bit-identical to R6/R7-validated):
//   A (opposite): [-oh(3), -oh(3), -ol(3), -ol(3), onh, onl, 1, 1]
//   B (query):    [ qh(3),  ql(3),  qh(3),  ql(3), 1, 1, qnh, qnl]
// ncs=1: each block owns 256 queries (one dir) and scans the WHOLE opposite
// side through a double-buffered LDS (OC=512 chunks, one barrier per chunk;
// next chunk's floats prefetched into 6 scalar regs before compute, packed
// after). Block-local mins are FINAL -> block computes sum of sqrt(2m) and
// writes ONE float. Second tiny kernel sums 256 partials. No atomics, no
// memset, deterministic.

#define NQ 256      // queries per block (4 waves x 64 cols)
#define OC 512      // opposite points per LDS chunk
#define LDR 24      // record stride in shorts (16 + 8 pad = 48 B), R7-proven
#define JF 2        // B-frags per wave

typedef short short8 __attribute__((ext_vector_type(8)));
typedef float f32x16 __attribute__((ext_vector_type(16)));

static __device__ inline unsigned short f2bf(float f) {
    __hip_bfloat16 h = __float2bfloat16(f);
    return *reinterpret_cast<unsigned short*>(&h);
}
static __device__ inline float bf2f(unsigned short u) {
    __hip_bfloat16 h;
    *reinterpret_cast<unsigned short*>(&h) = u;
    return __bfloat162float(h);
}
static __device__ inline void split_bf(float v, unsigned short& hi,
                                       unsigned short& lo) {
    hi = f2bf(v);
    lo = f2bf(v - bf2f(hi));
}
static __device__ inline float min3f(float a, float b, float c) {
    return fminf(fminf(a, b), c);   // clang fuses to v_min3_f32
}

// A-side record (negated coords), R7-exact content
static __device__ inline void pack_A(unsigned short* dst,
                                     float x, float y, float z) {
    unsigned short hx, lx, hy, ly, hz, lz, nh, nl;
    split_bf(x, hx, lx); split_bf(y, hy, ly); split_bf(z, hz, lz);
    float on = 0.5f * fmaf(x, x, fmaf(y, y, z * z));
    split_bf(on, nh, nl);
    const unsigned short ONE = 0x3F80;
    __align__(16) unsigned short r[16] = {
        (unsigned short)(hx ^ 0x8000), (unsigned short)(hy ^ 0x8000),
        (unsigned short)(hz ^ 0x8000), (unsigned short)(hx ^ 0x8000),
        (unsigned short)(hy ^ 0x8000), (unsigned short)(hz ^ 0x8000),
        (unsigned short)(lx ^ 0x8000), (unsigned short)(ly ^ 0x8000),
        (unsigned short)(lz ^ 0x8000), (unsigned short)(lx ^ 0x8000),
        (unsigned short)(ly ^ 0x8000), (unsigned short)(lz ^ 0x8000),
        nh, nl, ONE, ONE};
    *(short8*)(dst + 0) = ((const short8*)r)[0];
    *(short8*)(dst + 8) = ((const short8*)r)[1];
}

__global__ __launch_bounds__(256) void chamfer_main_kernel(
    const float* __restrict__ pred, const float* __restrict__ gt,
    float* __restrict__ partial,   // [grid] block sums
    int N, int qtiles, int nchunks)
{
    __align__(16) __shared__ unsigned short q_lds[NQ * LDR];      // 12 KB
    __align__(16) __shared__ unsigned short o_lds[2 * OC * LDR];  // 48 KB
    __shared__ float s_lds[4];

    int bid = blockIdx.x;
    int qt = bid % qtiles;  int t2 = bid / qtiles;
    int b  = t2 & 3;        int dir = t2 >> 2;

    const float* qpts = dir ? pred : gt;   // dir0: queries=gt (z)
    const float* opts = dir ? gt   : pred; // dir1: queries=pred (z2)
    const float* qb = qpts + (size_t)b * 3 * N;
    const float* ob = opts + (size_t)b * 3 * N;

    int tid = threadIdx.x;
    int lane = tid & 63, w = tid >> 6;
    int col = lane & 31, h = lane >> 5;
    const unsigned short ONE = 0x3F80;

    // ---- stage this block's 256 query records (B-side) ----
    {
        int qi = qt * NQ + tid;
        float x = qb[qi], y = qb[N + qi], z = qb[2 * N + qi];
        unsigned short hx, lx, hy, ly, hz, lz, nh, nl;
        split_bf(x, hx, lx); split_bf(y, hy, ly); split_bf(z, hz, lz);
        float qn = 0.5f * fmaf(x, x, fmaf(y, y, z * z));
        split_bf(qn, nh, nl);
        __align__(16) unsigned short r[16] = {
            hx, hy, hz, lx, ly, lz, hx, hy, hz, lx, ly, lz, ONE, ONE, nh, nl};
        unsigned short* dst = q_lds + tid * LDR;
        *(short8*)(dst + 0) = ((const short8*)r)[0];
        *(short8*)(dst + 8) = ((const short8*)r)[1];
    }
    // ---- prologue: stage opposite chunk 0 (2 records/thread) ----
    {
        int oi = tid;
        pack_A(o_lds + tid * LDR, ob[oi], ob[N + oi], ob[2 * N + oi]);
        oi = tid + 256;
        pack_A(o_lds + (tid + 256) * LDR, ob[oi], ob[N + oi], ob[2 * N + oi]);
    }
    __syncthreads();

    // B-frags: this wave's 64 query columns, registers for whole kernel
    short8 bfrag[JF];
    #pragma unroll
    for (int j = 0; j < JF; ++j)
        bfrag[j] = *(const short8*)(q_lds + (w * 64 + j * 32 + col) * LDR + h * 8);

    float mn[JF] = {3.0e38f, 3.0e38f};
    const f32x16 zero16 = {0.f};

    for (int c = 0; c < nchunks; ++c) {
        int cur = c & 1;
        // prefetch next chunk's raw floats (6 scalar regs, hides HBM/L2 lat)
        float p0x = 0.f, p0y = 0.f, p0z = 0.f, p1x = 0.f, p1y = 0.f, p1z = 0.f;
        bool pf = (c + 1 < nchunks);
        if (pf) {
            int oi = (c + 1) * OC + tid;
            p0x = ob[oi]; p0y = ob[N + oi]; p0z = ob[2 * N + oi];
            oi += 256;
            p1x = ob[oi]; p1y = ob[N + oi]; p1z = ob[2 * N + oi];
        }

        const unsigned short* ol = o_lds + cur * (OC * LDR);
        #pragma unroll 4
        for (int i = 0; i < OC / 32; ++i) {
            short8 af = *(const short8*)(ol + (i * 32 + col) * LDR + h * 8);
            #pragma unroll
            for (int j = 0; j < JF; ++j) {
                f32x16 acc = __builtin_amdgcn_mfma_f32_32x32x16_bf16(
                    af, bfrag[j], zero16, 0, 0, 0);
                float l0 = min3f(acc[0],  acc[1],  acc[2]);
                float l1 = min3f(acc[3],  acc[4],  acc[5]);
                float l2 = min3f(acc[6],  acc[7],  acc[8]);
                float l3 = min3f(acc[9],  acc[10], acc[11]);
                float l4 = min3f(acc[12], acc[13], acc[14]);
                float m0 = min3f(l0, l1, l2);
                float m1 = min3f(l3, l4, acc[15]);
                mn[j] = min3f(m0, m1, mn[j]);
            }
        }

        if (pf) {
            unsigned short* nb = o_lds + (cur ^ 1) * (OC * LDR);
            pack_A(nb + tid * LDR, p0x, p0y, p0z);
            pack_A(nb + (tid + 256) * LDR, p1x, p1y, p1z);
        }
        __syncthreads();
    }

    // fold k-half lane groups; mins are now FINAL for this block's queries
    #pragma unroll
    for (int j = 0; j < JF; ++j)
        mn[j] = fminf(mn[j], __shfl_xor(mn[j], 32, 64));

    // block-local sum of distances: d = sqrt(2m)
    float s = sqrtf(fmaxf(2.0f * mn[0], 0.0f)) +
              sqrtf(fmaxf(2.0f * mn[1], 0.0f));
    // sum within each 32-lane half (halves hold identical values post-fold)
    #pragma unroll
    for (int off = 1; off <= 16; off <<= 1)
        s += __shfl_xor(s, off, 64);
    if (lane == 0) s_lds[w] = s;
    __syncthreads();
    if (tid == 0)
        partial[bid] = (s_lds[0] + s_lds[1]) + (s_lds[2] + s_lds[3]);
}

__global__ __launch_bounds__(256) void chamfer_sum_kernel(
    const float* __restrict__ partial, float* __restrict__ out,
    int nb, float inv_b)
{
    __shared__ float sdata[256];
    float s = 0.0f;
    for (int i = threadIdx.x; i < nb; i += 256) s += partial[i];
    sdata[threadIdx.x] = s;
    __syncthreads();
    for (int off = 128; off > 0; off >>= 1) {
        if (threadIdx.x < off) sdata[threadIdx.x] += sdata[threadIdx.x + off];
        __syncthreads();
    }
    if (threadIdx.x == 0) out[0] = sdata[0] * inv_b;
}

extern "C" void kernel_launch(void* const* d_in, const int* in_sizes, int n_in,
                              void* d_out, int out_size, void* d_ws, size_t ws_size,
                              hipStream_t stream) {
    const float* pred = (const float*)d_in[0];
    const float* gt   = (const float*)d_in[1];
    const int B = 4, D = 3;
    const int N = in_sizes[0] / (B * D);   // 8192

    int qtiles  = N / NQ;          // 32
    int nchunks = N / OC;          // 16
    int nb = 2 * B * qtiles;       // 256 blocks

    float* partial = (float*)d_ws;  // [nb]

    chamfer_main_kernel<<<dim3(nb), dim3(256), 0, stream>>>(
        pred, gt, partial, N, qtiles, nchunks);
    chamfer_sum_kernel<<<dim3(1), dim3(256), 0, stream>>>(
        partial, (float*)d_out, nb, 1.0f / B);
}